// Round 4
// baseline (2365.142 us; speedup 1.0000x reference)
//
#include <hip/hip_runtime.h>
#include <hip/hip_bf16.h>

// Problem constants
#define BT    131072          // B*T = 32*4096
#define DD    96              // codebook dim
#define KCB   384             // codes per codebook
#define NCB   6               // codebooks
#define PROJ  192
#define W2V   768

// d_out layout (float32, concat in return order)
#define ZQT_OFF   0L
#define CODES_OFF 12582912L   // BT*DD
#define VQ_OFF    13369344L   // + BT*NCB
#define SEM_OFF   13369345L

// ws layout (bytes) — total ~340 KB (keep small: ws_size may be modest and
// overflowing d_ws corrupted adjacent allocations in R3)
#define ACC_OFF   0L          // 8 doubles: vq[0..5], sem[6]
#define E32_OFF   64L         // 2304 floats (np-pairwise fp32 ||e||^2)
#define W1T_OFF   9280L       // 192x96 bf16
#define W2T_OFF   46144L      // 768x192 bf16  (end: 341056)

typedef __attribute__((ext_vector_type(8))) short  bf16x8;
typedef __attribute__((ext_vector_type(4))) float  f32x4;

static __device__ __forceinline__ unsigned short f2bf(float x) {
    __hip_bfloat16 h = __float2bfloat16(x);
    return *reinterpret_cast<unsigned short*>(&h);
}
static __device__ __forceinline__ float comp(const float4& v, int c) {
    return c == 0 ? v.x : c == 1 ? v.y : c == 2 ? v.z : v.w;
}

// numpy pairwise_sum for n=96 (<=128 block): 8 strided accumulators over
// ascending blocks of 8, then tree combine ((r0+r1)+(r2+r3))+((r4+r5)+(r6+r7)).
static __device__ __forceinline__ float pairwise96_sq(const float4* r) {
    float a[8];
#pragma unroll
    for (int j = 0; j < 8; ++j) {
        const int c = j & 3, base = j >> 2;
        float x0 = comp(r[base], c);
        float s  = __fmul_rn(x0, x0);
#pragma unroll
        for (int t = 1; t < 12; ++t) {
            float x = comp(r[base + 2 * t], c);
            s = __fadd_rn(s, __fmul_rn(x, x));
        }
        a[j] = s;
    }
    return __fadd_rn(__fadd_rn(__fadd_rn(a[0], a[1]), __fadd_rn(a[2], a[3])),
                     __fadd_rn(__fadd_rn(a[4], a[5]), __fadd_rn(a[6], a[7])));
}

// ---------------------------------------------------------------- zero accums
__global__ void kzero(double* __restrict__ acc) {
    if (threadIdx.x < 8) acc[threadIdx.x] = 0.0;
}

// ------------------- fp32 codebook self-norms, numpy-pairwise order (n=96)
__global__ void kee(const float* __restrict__ cb, float* __restrict__ E32) {
    int c = blockIdx.x * 256 + threadIdx.x;
    if (c < NCB * KCB) {
        const float* row = cb + (size_t)c * DD;
        float a[8];
#pragma unroll
        for (int j = 0; j < 8; ++j) a[j] = __fmul_rn(row[j], row[j]);
        for (int t = 1; t < 12; ++t) {
#pragma unroll
            for (int j = 0; j < 8; ++j) {
                float x = row[8 * t + j];
                a[j] = __fadd_rn(a[j], __fmul_rn(x, x));
            }
        }
        E32[c] = __fadd_rn(__fadd_rn(__fadd_rn(a[0], a[1]), __fadd_rn(a[2], a[3])),
                           __fadd_rn(__fadd_rn(a[4], a[5]), __fadd_rn(a[6], a[7])));
    }
}

// ------------------------------------- transpose + bf16-cast w1, w2 for MFMA
__global__ void kwt(const float* __restrict__ w1, const float* __restrict__ w2,
                    __hip_bfloat16* __restrict__ w1T, __hip_bfloat16* __restrict__ w2T) {
    int i = blockIdx.x * 256 + threadIdx.x;
    if (i < DD * PROJ) {                  // w1 (96x192) -> w1T (192x96)
        int n = i / DD, k = i % DD;
        w1T[i] = __float2bfloat16(w1[k * PROJ + n]);
    }
    int j = i - DD * PROJ;
    if (j >= 0 && j < PROJ * W2V) {       // w2 (192x768) -> w2T (768x192)
        int n = j / PROJ, k = j % PROJ;
        w2T[j] = __float2bfloat16(w2[k * W2V + n]);
    }
}

// --------------------------------------------------------- Kernel Q: argmin
// Bit-exact replication of the np gold (validated in R3 call-1, absmax 0.0):
//   dist_k = fl32( fl32(S - C2_k) + E_k )
//   S  = numpy pairwise-8 sum of fl32(r_i^2)
//   C2 = sequential ascending-k FMA dot of (2*r) and e
//   E  = numpy pairwise-8 sum of fl32(e_i^2)
//   argmin = first index of min (strict <)
__global__ __launch_bounds__(128, 2) void kq(
        const float* __restrict__ z, const float* __restrict__ cb,
        const float* __restrict__ E32, float* __restrict__ dout) {
    __shared__ float et2[64 * DD];
    const int  tid  = threadIdx.x;
    const long tok0 = (long)blockIdx.x * 256 + tid;
    const long tok1 = tok0 + 128;

    float4 r0[24], r1[24];
    const float4* z4a = (const float4*)(z + tok0 * DD);
    const float4* z4b = (const float4*)(z + tok1 * DD);
#pragma unroll
    for (int i = 0; i < 24; ++i) { r0[i] = z4a[i]; r1[i] = z4b[i]; }

    for (int s = 0; s < NCB; ++s) {
        const float S0 = pairwise96_sq(r0);
        const float S1 = pairwise96_sq(r1);
        float m0v = 3.4e38f, m1v = 3.4e38f;
        int   b0 = 0, b1 = 0;
        for (int c = 0; c < 6; ++c) {
            __syncthreads();
            const float4* src = (const float4*)(cb + (size_t)(s * KCB + c * 64) * DD);
            float4* dst = (float4*)et2;
#pragma unroll
            for (int j = 0; j < 12; ++j) {
                float4 v = src[j * 128 + tid];
                v.x = __fmul_rn(2.f, v.x); v.y = __fmul_rn(2.f, v.y);
                v.z = __fmul_rn(2.f, v.z); v.w = __fmul_rn(2.f, v.w);
                dst[j * 128 + tid] = v;
            }
            __syncthreads();
            const float* eec = E32 + s * KCB + c * 64;
#pragma unroll 2
            for (int kl = 0; kl < 64; ++kl) {
                const float4* e4p = ((const float4*)et2) + kl * 24;
                float a0 = 0.f, a1 = 0.f;
#pragma unroll
                for (int i = 0; i < 24; ++i) {
                    float4 e = e4p[i];
                    a0 = fmaf(r0[i].x, e.x, a0); a0 = fmaf(r0[i].y, e.y, a0);
                    a0 = fmaf(r0[i].z, e.z, a0); a0 = fmaf(r0[i].w, e.w, a0);
                    a1 = fmaf(r1[i].x, e.x, a1); a1 = fmaf(r1[i].y, e.y, a1);
                    a1 = fmaf(r1[i].z, e.z, a1); a1 = fmaf(r1[i].w, e.w, a1);
                }
                float d0 = __fadd_rn(__fsub_rn(S0, a0), eec[kl]);
                float d1 = __fadd_rn(__fsub_rn(S1, a1), eec[kl]);
                const int kk = c * 64 + kl;
                if (d0 < m0v) { m0v = d0; b0 = kk; }
                if (d1 < m1v) { m1v = d1; b1 = kk; }
            }
        }
        dout[CODES_OFF + tok0 * NCB + s] = (float)b0;
        dout[CODES_OFF + tok1 * NCB + s] = (float)b1;
        // straight-through residual update, exact fp32 elementwise sequence
        const float4* q04 = (const float4*)(cb + ((size_t)s * KCB + b0) * DD);
        const float4* q14 = (const float4*)(cb + ((size_t)s * KCB + b1) * DD);
#pragma unroll
        for (int i = 0; i < 24; ++i) {
            float4 qa = q04[i], qb = q14[i];
            float4 da, sa, db, sb;
            da.x = __fsub_rn(qa.x, r0[i].x); da.y = __fsub_rn(qa.y, r0[i].y);
            da.z = __fsub_rn(qa.z, r0[i].z); da.w = __fsub_rn(qa.w, r0[i].w);
            sa.x = __fadd_rn(r0[i].x, da.x); sa.y = __fadd_rn(r0[i].y, da.y);
            sa.z = __fadd_rn(r0[i].z, da.z); sa.w = __fadd_rn(r0[i].w, da.w);
            r0[i].x = __fsub_rn(r0[i].x, sa.x); r0[i].y = __fsub_rn(r0[i].y, sa.y);
            r0[i].z = __fsub_rn(r0[i].z, sa.z); r0[i].w = __fsub_rn(r0[i].w, sa.w);
            db.x = __fsub_rn(qb.x, r1[i].x); db.y = __fsub_rn(qb.y, r1[i].y);
            db.z = __fsub_rn(qb.z, r1[i].z); db.w = __fsub_rn(qb.w, r1[i].w);
            sb.x = __fadd_rn(r1[i].x, db.x); sb.y = __fadd_rn(r1[i].y, db.y);
            sb.z = __fadd_rn(r1[i].z, db.z); sb.w = __fadd_rn(r1[i].w, db.w);
            r1[i].x = __fsub_rn(r1[i].x, sb.x); r1[i].y = __fsub_rn(r1[i].y, sb.y);
            r1[i].z = __fsub_rn(r1[i].z, sb.z); r1[i].w = __fsub_rn(r1[i].w, sb.w);
        }
    }
}

// ------------------------------------------- Kernel R: replay from codes
// Identical fp32 elementwise chain -> z_q_total; fp64 vq sums.
__global__ __launch_bounds__(256) void kr(
        const float* __restrict__ z, const float* __restrict__ cb,
        const float* __restrict__ codesf, float* __restrict__ zqt_out,
        double* __restrict__ acc) {
    const long tok = (long)blockIdx.x * 256 + threadIdx.x;
    float4 r[24], zqt[24];
    const float4* z4 = (const float4*)(z + tok * DD);
#pragma unroll
    for (int i = 0; i < 24; ++i) r[i] = z4[i];
    double ls[NCB];
#pragma unroll
    for (int s = 0; s < NCB; ++s) {
        const int idx = (int)codesf[tok * NCB + s];
        const float4* q4 = (const float4*)(cb + (size_t)(s * KCB + idx) * DD);
        double a = 0.0;
#pragma unroll
        for (int i = 0; i < 24; ++i) {
            float4 q = q4[i];
            float4 d, st;
            d.x = __fsub_rn(q.x, r[i].x); d.y = __fsub_rn(q.y, r[i].y);
            d.z = __fsub_rn(q.z, r[i].z); d.w = __fsub_rn(q.w, r[i].w);
            st.x = __fadd_rn(r[i].x, d.x); st.y = __fadd_rn(r[i].y, d.y);
            st.z = __fadd_rn(r[i].z, d.z); st.w = __fadd_rn(r[i].w, d.w);
            if (s == 0) {
                zqt[i] = st;
            } else {
                zqt[i].x = __fadd_rn(zqt[i].x, st.x); zqt[i].y = __fadd_rn(zqt[i].y, st.y);
                zqt[i].z = __fadd_rn(zqt[i].z, st.z); zqt[i].w = __fadd_rn(zqt[i].w, st.w);
            }
            r[i].x = __fsub_rn(r[i].x, st.x); r[i].y = __fsub_rn(r[i].y, st.y);
            r[i].z = __fsub_rn(r[i].z, st.z); r[i].w = __fsub_rn(r[i].w, st.w);
            a += (double)d.x * (double)d.x; a += (double)d.y * (double)d.y;
            a += (double)d.z * (double)d.z; a += (double)d.w * (double)d.w;
        }
        ls[s] = a;
    }
    float4* o4 = (float4*)(zqt_out + tok * DD);
#pragma unroll
    for (int i = 0; i < 24; ++i) o4[i] = zqt[i];
#pragma unroll
    for (int s = 0; s < NCB; ++s) {
        double v = ls[s];
        for (int off = 32; off > 0; off >>= 1) v += __shfl_down(v, off, 64);
        if ((threadIdx.x & 63) == 0) atomicAdd(&acc[s], v);
    }
}

// --------------------------- Kernel H: fused semantic head (bf16 MFMA)
// Recomputes stage-0 straight-through values from z + cb + codes (identical
// fp32 op sequence as kr/kq: st = r + (q - r)), builds A-fragments directly.
__global__ __launch_bounds__(256) void kh(
        const float* __restrict__ z, const float* __restrict__ cb,
        const float* __restrict__ codesf,
        const __hip_bfloat16* __restrict__ w1T, const float* __restrict__ b1,
        const __hip_bfloat16* __restrict__ w2T, const float* __restrict__ b2,
        const float* __restrict__ tgt, double* __restrict__ sem_acc) {
    __shared__ unsigned short hs[64][PROJ + 8];   // +8 pad: conflict-free b128
    const int lane = threadIdx.x & 63, wv = threadIdx.x >> 6;
    const int col  = lane & 15, quad = lane >> 4;
    const long m0  = (long)blockIdx.x * 64 + wv * 16;

    // phase 1 A-fragments: this lane's row = token m0+col, k = ks*32+quad*8..+8
    const long tokrow = m0 + col;
    const int  code0  = (int)codesf[tokrow * NCB];
    const float* zr = z  + tokrow * DD;
    const float* qr = cb + (size_t)code0 * DD;
    bf16x8 a1f[3];
#pragma unroll
    for (int ks = 0; ks < 3; ++ks) {
        const int k0 = ks * 32 + quad * 8;
        bf16x8 v;
#pragma unroll
        for (int j = 0; j < 8; ++j) {
            float r = zr[k0 + j], q = qr[k0 + j];
            float d  = __fsub_rn(q, r);
            float st = __fadd_rn(r, d);
            v[j] = (short)f2bf(st);
        }
        a1f[ks] = v;
    }
    for (int nt = 0; nt < 12; ++nt) {
        const int n0 = nt * 16;
        f32x4 accv = {0.f, 0.f, 0.f, 0.f};
        const unsigned short* bw = (const unsigned short*)w1T + (n0 + col) * DD + quad * 8;
#pragma unroll
        for (int ks = 0; ks < 3; ++ks) {
            bf16x8 bf = *(const bf16x8*)(bw + ks * 32);
            accv = __builtin_amdgcn_mfma_f32_16x16x32_bf16(a1f[ks], bf, accv, 0, 0, 0);
        }
#pragma unroll
        for (int r = 0; r < 4; ++r) {
            float x = accv[r] + b1[n0 + col];
            float g = 0.5f * x * (1.0f + erff(x * 0.70710678118654752440f));
            hs[wv * 16 + quad * 4 + r][n0 + col] = f2bf(g);
        }
    }
    __syncthreads();
    bf16x8 a2f[6];
#pragma unroll
    for (int ks = 0; ks < 6; ++ks)
        a2f[ks] = *(const bf16x8*)(&hs[wv * 16 + col][ks * 32 + quad * 8]);
    double lsum = 0.0;
    for (int nt = 0; nt < 48; ++nt) {
        const int n0 = nt * 16;
        f32x4 accv = {0.f, 0.f, 0.f, 0.f};
        const unsigned short* bw = (const unsigned short*)w2T + (size_t)(n0 + col) * PROJ + quad * 8;
#pragma unroll
        for (int ks = 0; ks < 6; ++ks) {
            bf16x8 bf = *(const bf16x8*)(bw + ks * 32);
            accv = __builtin_amdgcn_mfma_f32_16x16x32_bf16(a2f[ks], bf, accv, 0, 0, 0);
        }
#pragma unroll
        for (int r = 0; r < 4; ++r) {
            float pred = accv[r] + b2[n0 + col];
            float dt = pred - tgt[(m0 + quad * 4 + r) * (long)W2V + n0 + col];
            lsum += (double)dt * (double)dt;
        }
    }
    for (int off = 32; off > 0; off >>= 1) lsum += __shfl_down(lsum, off, 64);
    if (lane == 0) atomicAdd(sem_acc, lsum);
}

// ---------------------------------------------------------------- finalize
__global__ void kf(const double* __restrict__ acc, float* __restrict__ dout) {
    if (threadIdx.x == 0 && blockIdx.x == 0) {
        float vq = 0.f;
        for (int s = 0; s < NCB; ++s) {
            float l = (float)(acc[s] / 12582912.0);   // mean over B*T*D
            vq = vq + l;          // embedding_loss
            vq = vq + 0.5f * l;   // COMMIT * commitment_loss (identical value)
        }
        dout[VQ_OFF]  = vq;
        dout[SEM_OFF] = (float)(acc[6] / 100663296.0); // mean over B*T*W2V
    }
}

extern "C" void kernel_launch(void* const* d_in, const int* in_sizes, int n_in,
                              void* d_out, int out_size, void* d_ws, size_t ws_size,
                              hipStream_t stream) {
    const float* z   = (const float*)d_in[0];
    const float* tgt = (const float*)d_in[1];
    const float* cb  = (const float*)d_in[2];
    const float* w1  = (const float*)d_in[3];
    const float* b1  = (const float*)d_in[4];
    const float* w2  = (const float*)d_in[5];
    const float* b2  = (const float*)d_in[6];
    float* out = (float*)d_out;
    char*  ws  = (char*)d_ws;

    double*          accs = (double*)(ws + ACC_OFF);
    float*           E32  = (float*)(ws + E32_OFF);
    __hip_bfloat16*  w1T  = (__hip_bfloat16*)(ws + W1T_OFF);
    __hip_bfloat16*  w2T  = (__hip_bfloat16*)(ws + W2T_OFF);

    kzero<<<dim3(1), dim3(64), 0, stream>>>(accs);
    kee  <<<dim3(9), dim3(256), 0, stream>>>(cb, E32);
    kwt  <<<dim3(648), dim3(256), 0, stream>>>(w1, w2, w1T, w2T);
    kq   <<<dim3(512), dim3(128), 0, stream>>>(z, cb, E32, out);
    kr   <<<dim3(512), dim3(256), 0, stream>>>(z, cb, out + CODES_OFF, out, accs);
    kh   <<<dim3(2048), dim3(256), 0, stream>>>(z, cb, out + CODES_OFF,
                                                w1T, b1, w2T, b2, tgt, accs + 6);
    kf   <<<dim3(1), dim3(64), 0, stream>>>(accs, out);
}